// Round 1
// baseline (1626.825 us; speedup 1.0000x reference)
//
#include <hip/hip_runtime.h>
#include <hip/hip_bf16.h>
#include <cstdint>
#include <cstddef>

#define N_NODES 65536
#define N_EDGES 1048576
#define N_GRAPHS 128
#define NPG 512
#define IN_DIM 64
#define HID 128
#define BN_EPS 1e-5f

// ---------------- CSR build ----------------
__global__ __launch_bounds__(256) void hist_kernel(const int* __restrict__ dst,
                                                   int* __restrict__ deg) {
  int e = blockIdx.x * 256 + threadIdx.x;
  if (e < N_EDGES) atomicAdd(&deg[dst[e]], 1);
}

__global__ __launch_bounds__(256) void dis_kernel(const int* __restrict__ deg,
                                                  float* __restrict__ dis) {
  int n = blockIdx.x * 256 + threadIdx.x;
  if (n < N_NODES) dis[n] = 1.0f / sqrtf((float)deg[n] + 1.0f);
}

// single block of 1024 threads; each thread scans 64 contiguous counters
__global__ __launch_bounds__(1024) void scan_kernel(const int* __restrict__ deg,
                                                    int* __restrict__ offsets,
                                                    int* __restrict__ cursor) {
  __shared__ int sums[1024];
  int t = threadIdx.x;
  int base = t * 64;
  const int4* dp = (const int4*)(deg + base);
  int s = 0;
#pragma unroll
  for (int i = 0; i < 16; i++) {
    int4 v = dp[i];
    s += v.x + v.y + v.z + v.w;
  }
  sums[t] = s;
  __syncthreads();
  for (int off = 1; off < 1024; off <<= 1) {
    int v = (t >= off) ? sums[t - off] : 0;
    __syncthreads();
    sums[t] += v;
    __syncthreads();
  }
  int run = (t == 0) ? 0 : sums[t - 1];
#pragma unroll
  for (int i = 0; i < 16; i++) {
    int4 v = dp[i];
    int idx = base + i * 4;
    offsets[idx] = run; cursor[idx] = run; run += v.x;
    offsets[idx + 1] = run; cursor[idx + 1] = run; run += v.y;
    offsets[idx + 2] = run; cursor[idx + 2] = run; run += v.z;
    offsets[idx + 3] = run; cursor[idx + 3] = run; run += v.w;
  }
  if (t == 1023) offsets[N_NODES] = run;
}

__global__ __launch_bounds__(256) void fill_kernel(const int* __restrict__ src,
                                                   const int* __restrict__ dst,
                                                   int* __restrict__ cursor,
                                                   int* __restrict__ csr) {
  int e = blockIdx.x * 256 + threadIdx.x;
  if (e < N_EDGES) {
    int d = dst[e];
    int slot = atomicAdd(&cursor[d], 1);
    csr[slot] = src[e];
  }
}

// ---------------- aggregation (gather over CSR) ----------------
// z[n] = sum_{s in in(n)} dis[s]*dis[n]*h[s]  +  dis[n]^2 * h[n]
__global__ __launch_bounds__(256) void agg64_kernel(const float* __restrict__ x,
                                                    const float* __restrict__ dis,
                                                    const int* __restrict__ offsets,
                                                    const int* __restrict__ csr,
                                                    float* __restrict__ z) {
  int node = blockIdx.x * 4 + (threadIdx.x >> 6);
  int lane = threadIdx.x & 63;
  float dn = dis[node];
  float acc = x[(size_t)node * 64 + lane] * dn * dn;
  int beg = offsets[node], end = offsets[node + 1];
  for (int k = beg; k < end; k++) {
    int s = csr[k];
    acc = fmaf(dn * dis[s], x[(size_t)s * 64 + lane], acc);
  }
  z[(size_t)node * 64 + lane] = acc;
}

__global__ __launch_bounds__(256) void agg128_kernel(const float* __restrict__ h,
                                                     const float* __restrict__ dis,
                                                     const int* __restrict__ offsets,
                                                     const int* __restrict__ csr,
                                                     float* __restrict__ z) {
  int node = blockIdx.x * 4 + (threadIdx.x >> 6);
  int lane = threadIdx.x & 63;
  float dn = dis[node];
  float sn = dn * dn;
  const float* hr = h + (size_t)node * 128;
  float a0 = hr[lane] * sn;
  float a1 = hr[lane + 64] * sn;
  int beg = offsets[node], end = offsets[node + 1];
  for (int k = beg; k < end; k++) {
    int s = csr[k];
    float w = dn * dis[s];
    const float* hs = h + (size_t)s * 128;
    a0 = fmaf(w, hs[lane], a0);
    a1 = fmaf(w, hs[lane + 64], a1);
  }
  z[(size_t)node * 128 + lane] = a0;
  z[(size_t)node * 128 + lane + 64] = a1;
}

// ---------------- fused fp32 GEMM: C = A[N,K] * B (+bias, +BN, +ReLU) ----------------
// BTRANS=false: B is [K,O] row-major (h @ W). BTRANS=true: B is [O,K] row-major (h @ W^T).
template <int K, int O, bool BTRANS, bool DOBN, bool DORELU>
__global__ __launch_bounds__(256) void gemm_fused(const float* __restrict__ A,
                                                  const float* __restrict__ B,
                                                  const float* __restrict__ bias,
                                                  const float* __restrict__ gamma,
                                                  const float* __restrict__ beta,
                                                  const float* __restrict__ mean,
                                                  const float* __restrict__ var,
                                                  float* __restrict__ C) {
  constexpr int BM = 64, BO = 128, BK = 16;
  __shared__ float As[BK][BM + 4];  // [k][m], padded rows (68 floats, 16B-aligned)
  __shared__ float Bs[BK][BO + 4];  // [k][o], padded rows (132 floats, 16B-aligned)
  int tid = threadIdx.x;
  int m0 = blockIdx.x * BM;
  int o0 = blockIdx.y * BO;
  int tm = tid >> 4;  // 0..15 -> rows tm*4..tm*4+3
  int to = tid & 15;  // 0..15 -> cols to*8..to*8+7

  float acc[4][8];
#pragma unroll
  for (int i = 0; i < 4; i++)
#pragma unroll
    for (int j = 0; j < 8; j++) acc[i][j] = 0.0f;

  int arow = tid >> 2, aseg = tid & 3;

  for (int k0 = 0; k0 < K; k0 += BK) {
    float4 a4 = *(const float4*)&A[(size_t)(m0 + arow) * K + k0 + aseg * 4];
    float4 b0, b1;
    int bo = 0, bkh = 0;
    if (BTRANS) {
      bo = tid & 127;
      bkh = (tid >> 7) * 8;
      const float* bp = &B[(size_t)(o0 + bo) * K + k0 + bkh];
      b0 = *(const float4*)bp;
      b1 = *(const float4*)(bp + 4);
    } else {
      bkh = tid >> 4;       // k within tile
      bo = (tid & 15) * 8;  // col start
      const float* bp = &B[(size_t)(k0 + bkh) * O + o0 + bo];
      b0 = *(const float4*)bp;
      b1 = *(const float4*)(bp + 4);
    }
    __syncthreads();  // previous iteration's compute done before overwrite
    As[aseg * 4 + 0][arow] = a4.x;
    As[aseg * 4 + 1][arow] = a4.y;
    As[aseg * 4 + 2][arow] = a4.z;
    As[aseg * 4 + 3][arow] = a4.w;
    if (BTRANS) {
      Bs[bkh + 0][bo] = b0.x; Bs[bkh + 1][bo] = b0.y;
      Bs[bkh + 2][bo] = b0.z; Bs[bkh + 3][bo] = b0.w;
      Bs[bkh + 4][bo] = b1.x; Bs[bkh + 5][bo] = b1.y;
      Bs[bkh + 6][bo] = b1.z; Bs[bkh + 7][bo] = b1.w;
    } else {
      *(float4*)&Bs[bkh][bo] = b0;
      *(float4*)&Bs[bkh][bo + 4] = b1;
    }
    __syncthreads();
#pragma unroll
    for (int k = 0; k < BK; k++) {
      float4 av = *(const float4*)&As[k][tm * 4];
      float4 bv0 = *(const float4*)&Bs[k][to * 8];
      float4 bv1 = *(const float4*)&Bs[k][to * 8 + 4];
      float am[4] = {av.x, av.y, av.z, av.w};
      float bm[8] = {bv0.x, bv0.y, bv0.z, bv0.w, bv1.x, bv1.y, bv1.z, bv1.w};
#pragma unroll
      for (int i = 0; i < 4; i++)
#pragma unroll
        for (int j = 0; j < 8; j++) acc[i][j] = fmaf(am[i], bm[j], acc[i][j]);
    }
  }

  // epilogue: v = acc + bias; BN: (v-mean)*gamma*rsqrt(var+eps)+beta; ReLU
  float cs[8], cb[8];
#pragma unroll
  for (int j = 0; j < 8; j++) {
    int c = o0 + to * 8 + j;
    float b = bias[c];
    if (DOBN) {
      float sc = gamma[c] * rsqrtf(var[c] + BN_EPS);
      cs[j] = sc;
      cb[j] = (b - mean[c]) * sc + beta[c];
    } else {
      cs[j] = 1.0f;
      cb[j] = b;
    }
  }
#pragma unroll
  for (int i = 0; i < 4; i++) {
    int row = m0 + tm * 4 + i;
    float out[8];
#pragma unroll
    for (int j = 0; j < 8; j++) {
      float v = fmaf(acc[i][j], cs[j], cb[j]);
      out[j] = DORELU ? fmaxf(v, 0.0f) : v;
    }
    float4* cp = (float4*)&C[(size_t)row * O + o0 + to * 8];
    cp[0] = make_float4(out[0], out[1], out[2], out[3]);
    cp[1] = make_float4(out[4], out[5], out[6], out[7]);
  }
}

// ---------------- attention: one block per (graph, head), 2 queries/thread ----------------
__global__ __launch_bounds__(256) void attn_kernel(const float* __restrict__ qkv,
                                                   float* __restrict__ obuf) {
  int g = blockIdx.x >> 2;
  int h = blockIdx.x & 3;
  int t = threadIdx.x;  // owns queries t and t+256
  const float scale = 0.17677669529663687f;  // 1/sqrt(32)

  __shared__ union SM {
    struct { float k[64][32]; float v[64][32]; } kv;
    float ob[128][33];
  } sm;

  size_t gbase = (size_t)g * NPG;

  float q1[32], q2[32];
  {
    const float* qp1 = &qkv[(gbase + t) * 384 + h * 32];
    const float* qp2 = &qkv[(gbase + t + 256) * 384 + h * 32];
#pragma unroll
    for (int i = 0; i < 8; i++) {
      float4 v1 = *(const float4*)(qp1 + i * 4);
      float4 v2 = *(const float4*)(qp2 + i * 4);
      q1[i * 4 + 0] = v1.x; q1[i * 4 + 1] = v1.y; q1[i * 4 + 2] = v1.z; q1[i * 4 + 3] = v1.w;
      q2[i * 4 + 0] = v2.x; q2[i * 4 + 1] = v2.y; q2[i * 4 + 2] = v2.z; q2[i * 4 + 3] = v2.w;
    }
  }

  int sj = t >> 2;         // staging row 0..63
  int sc = (t & 3) * 8;    // staging col start (8 floats = 2 float4)

  // ---- phase A: row max ----
  float m1 = -3.0e38f, m2 = -3.0e38f;
  for (int ch = 0; ch < 8; ch++) {
    __syncthreads();
    {
      const float* kp = &qkv[(gbase + ch * 64 + sj) * 384 + 128 + h * 32 + sc];
      *(float4*)&sm.kv.k[sj][sc] = *(const float4*)kp;
      *(float4*)&sm.kv.k[sj][sc + 4] = *(const float4*)(kp + 4);
    }
    __syncthreads();
    for (int j = 0; j < 64; j++) {
      float s1 = 0.0f, s2 = 0.0f;
#pragma unroll
      for (int d = 0; d < 32; d++) {
        float kv = sm.kv.k[j][d];
        s1 = fmaf(q1[d], kv, s1);
        s2 = fmaf(q2[d], kv, s2);
      }
      m1 = fmaxf(m1, s1 * scale);
      m2 = fmaxf(m2, s2 * scale);
    }
  }

  // ---- phase B: exp-accumulate ----
  float l1 = 0.0f, l2 = 0.0f;
  float o1[32], o2[32];
#pragma unroll
  for (int d = 0; d < 32; d++) { o1[d] = 0.0f; o2[d] = 0.0f; }

  for (int ch = 0; ch < 8; ch++) {
    __syncthreads();
    {
      const float* kp = &qkv[(gbase + ch * 64 + sj) * 384 + 128 + h * 32 + sc];
      *(float4*)&sm.kv.k[sj][sc] = *(const float4*)kp;
      *(float4*)&sm.kv.k[sj][sc + 4] = *(const float4*)(kp + 4);
      const float* vp = kp + 128;
      *(float4*)&sm.kv.v[sj][sc] = *(const float4*)vp;
      *(float4*)&sm.kv.v[sj][sc + 4] = *(const float4*)(vp + 4);
    }
    __syncthreads();
    for (int j = 0; j < 64; j++) {
      float s1 = 0.0f, s2 = 0.0f;
#pragma unroll
      for (int d = 0; d < 32; d++) {
        float kv = sm.kv.k[j][d];
        s1 = fmaf(q1[d], kv, s1);
        s2 = fmaf(q2[d], kv, s2);
      }
      float p1 = __expf(fmaf(s1, scale, -m1));
      float p2 = __expf(fmaf(s2, scale, -m2));
      l1 += p1;
      l2 += p2;
#pragma unroll
      for (int d = 0; d < 32; d++) {
        float vv = sm.kv.v[j][d];
        o1[d] = fmaf(p1, vv, o1[d]);
        o2[d] = fmaf(p2, vv, o2[d]);
      }
    }
  }

  float inv1 = 1.0f / l1, inv2 = 1.0f / l2;

  // ---- write out via LDS transpose for coalesced stores ----
  // pass p covers global rows [p*128, p*128+128)
#pragma unroll
  for (int p = 0; p < 4; p++) {
    __syncthreads();
    bool mine = (p & 1) ? (t >= 128) : (t < 128);
    if (mine) {
      int nn = t & 127;
      if (p < 2) {
#pragma unroll
        for (int d = 0; d < 32; d++) sm.ob[nn][d] = o1[d] * inv1;
      } else {
#pragma unroll
        for (int d = 0; d < 32; d++) sm.ob[nn][d] = o2[d] * inv2;
      }
    }
    __syncthreads();
#pragma unroll
    for (int it = 0; it < 4; it++) {
      int idx = it * 256 + t;
      int rr = idx >> 3;
      int c4 = (idx & 7) * 4;
      float4 v = make_float4(sm.ob[rr][c4], sm.ob[rr][c4 + 1], sm.ob[rr][c4 + 2],
                             sm.ob[rr][c4 + 3]);
      *(float4*)&obuf[((size_t)(gbase + p * 128 + rr)) * 128 + h * 32 + c4] = v;
    }
  }
}

// ---------------- mean pool ----------------
__global__ __launch_bounds__(128) void pool_kernel(const float* __restrict__ fin,
                                                   float* __restrict__ emb) {
  int g = blockIdx.x, c = threadIdx.x;
  const float* p = fin + (size_t)g * NPG * HID + c;
  float s = 0.0f;
  for (int i = 0; i < NPG; i++) s += p[(size_t)i * HID];
  emb[g * HID + c] = s * (1.0f / NPG);
}

extern "C" void kernel_launch(void* const* d_in, const int* in_sizes, int n_in,
                              void* d_out, int out_size, void* d_ws, size_t ws_size,
                              hipStream_t stream) {
  (void)in_sizes; (void)n_in; (void)out_size; (void)ws_size;
  const float* x          = (const float*)d_in[0];
  const float* W0         = (const float*)d_in[1];
  const float* b0         = (const float*)d_in[2];
  const float* Wh         = (const float*)d_in[3];
  const float* bh         = (const float*)d_in[4];
  const float* bn_gamma   = (const float*)d_in[5];
  const float* bn_beta    = (const float*)d_in[6];
  const float* bn_mean    = (const float*)d_in[7];
  const float* bn_var     = (const float*)d_in[8];
  const float* attn_in_w  = (const float*)d_in[9];
  const float* attn_in_b  = (const float*)d_in[10];
  const float* attn_out_w = (const float*)d_in[11];
  const float* attn_out_b = (const float*)d_in[12];
  const int* edge_index   = (const int*)d_in[13];
  const int* src = edge_index;
  const int* dst = edge_index + N_EDGES;

  char* ws = (char*)d_ws;
  size_t off = 0;
  auto alloc = [&](size_t bytes) -> void* {
    void* p = ws + off;
    off += (bytes + 255) & ~(size_t)255;
    return p;
  };
  int*   deg     = (int*)alloc((size_t)N_NODES * 4);
  int*   offsets = (int*)alloc((size_t)(N_NODES + 1) * 4);
  int*   cursor  = (int*)alloc((size_t)N_NODES * 4);
  int*   csr     = (int*)alloc((size_t)N_EDGES * 4);
  float* dis     = (float*)alloc((size_t)N_NODES * 4);
  float* bufA    = (float*)alloc((size_t)N_NODES * HID * 4);
  float* bufB    = (float*)alloc((size_t)N_NODES * HID * 4);
  float* qkvb    = (float*)alloc((size_t)N_NODES * 384 * 4);

  float* fin = (float*)d_out;                       // [N, HID]
  float* emb = fin + (size_t)N_NODES * HID;         // [G, HID]

  hipMemsetAsync(deg, 0, (size_t)N_NODES * 4, stream);
  hist_kernel<<<N_EDGES / 256, 256, 0, stream>>>(dst, deg);
  dis_kernel<<<N_NODES / 256, 256, 0, stream>>>(deg, dis);
  scan_kernel<<<1, 1024, 0, stream>>>(deg, offsets, cursor);
  fill_kernel<<<N_EDGES / 256, 256, 0, stream>>>(src, dst, cursor, csr);

  dim3 gemm_grid(N_NODES / 64, 1);
  // layer 0: aggregate x (64-dim), then z @ W0 -> bufA
  agg64_kernel<<<N_NODES / 4, 256, 0, stream>>>(x, dis, offsets, csr, bufB);
  gemm_fused<64, 128, false, true, true><<<gemm_grid, 256, 0, stream>>>(
      bufB, W0, b0, bn_gamma, bn_beta, bn_mean, bn_var, bufA);
  // layers 1..3
  for (int L = 0; L < 3; L++) {
    agg128_kernel<<<N_NODES / 4, 256, 0, stream>>>(bufA, dis, offsets, csr, bufB);
    gemm_fused<128, 128, false, true, true><<<gemm_grid, 256, 0, stream>>>(
        bufB, Wh + (size_t)L * HID * HID, bh + (size_t)L * HID,
        bn_gamma + (size_t)(L + 1) * HID, bn_beta + (size_t)(L + 1) * HID,
        bn_mean + (size_t)(L + 1) * HID, bn_var + (size_t)(L + 1) * HID, bufA);
  }
  // qkv = f @ attn_in_w^T + attn_in_b
  dim3 qkv_grid(N_NODES / 64, 3);
  gemm_fused<128, 384, true, false, false><<<qkv_grid, 256, 0, stream>>>(
      bufA, attn_in_w, attn_in_b, nullptr, nullptr, nullptr, nullptr, qkvb);
  // attention -> bufB (head-interleaved [N, HID])
  attn_kernel<<<N_GRAPHS * 4, 256, 0, stream>>>(qkvb, bufB);
  // final = o @ attn_out_w^T + attn_out_b -> d_out
  gemm_fused<128, 128, true, false, false><<<gemm_grid, 256, 0, stream>>>(
      bufB, attn_out_w, attn_out_b, nullptr, nullptr, nullptr, nullptr, fin);
  // graph mean pool
  pool_kernel<<<N_GRAPHS, 128, 0, stream>>>(fin, emb);
}

// Round 2
// 1235.073 us; speedup vs baseline: 1.3172x; 1.3172x over previous
//
#include <hip/hip_runtime.h>
#include <hip/hip_bf16.h>
#include <cstdint>
#include <cstddef>

#define N_NODES 65536
#define N_EDGES 1048576
#define N_GRAPHS 128
#define NPG 512
#define IN_DIM 64
#define HID 128
#define BN_EPS 1e-5f

// ---------------- CSR build ----------------
__global__ __launch_bounds__(256) void hist_kernel(const int* __restrict__ dst,
                                                   int* __restrict__ deg) {
  int e = blockIdx.x * 256 + threadIdx.x;
  if (e < N_EDGES) atomicAdd(&deg[dst[e]], 1);
}

__global__ __launch_bounds__(256) void dis_kernel(const int* __restrict__ deg,
                                                  float* __restrict__ dis) {
  int n = blockIdx.x * 256 + threadIdx.x;
  if (n < N_NODES) dis[n] = 1.0f / sqrtf((float)deg[n] + 1.0f);
}

// single block of 1024 threads; each thread scans 64 contiguous counters
__global__ __launch_bounds__(1024) void scan_kernel(const int* __restrict__ deg,
                                                    int* __restrict__ offsets,
                                                    int* __restrict__ cursor) {
  __shared__ int sums[1024];
  int t = threadIdx.x;
  int base = t * 64;
  const int4* dp = (const int4*)(deg + base);
  int s = 0;
#pragma unroll
  for (int i = 0; i < 16; i++) {
    int4 v = dp[i];
    s += v.x + v.y + v.z + v.w;
  }
  sums[t] = s;
  __syncthreads();
  for (int off = 1; off < 1024; off <<= 1) {
    int v = (t >= off) ? sums[t - off] : 0;
    __syncthreads();
    sums[t] += v;
    __syncthreads();
  }
  int run = (t == 0) ? 0 : sums[t - 1];
#pragma unroll
  for (int i = 0; i < 16; i++) {
    int4 v = dp[i];
    int idx = base + i * 4;
    offsets[idx] = run; cursor[idx] = run; run += v.x;
    offsets[idx + 1] = run; cursor[idx + 1] = run; run += v.y;
    offsets[idx + 2] = run; cursor[idx + 2] = run; run += v.z;
    offsets[idx + 3] = run; cursor[idx + 3] = run; run += v.w;
  }
  if (t == 1023) offsets[N_NODES] = run;
}

__global__ __launch_bounds__(256) void fill_kernel(const int* __restrict__ src,
                                                   const int* __restrict__ dst,
                                                   int* __restrict__ cursor,
                                                   int* __restrict__ csr) {
  int e = blockIdx.x * 256 + threadIdx.x;
  if (e < N_EDGES) {
    int d = dst[e];
    int slot = atomicAdd(&cursor[d], 1);
    csr[slot] = src[e];
  }
}

// ---------------- aggregation (gather over CSR) ----------------
__global__ __launch_bounds__(256) void agg64_kernel(const float* __restrict__ x,
                                                    const float* __restrict__ dis,
                                                    const int* __restrict__ offsets,
                                                    const int* __restrict__ csr,
                                                    float* __restrict__ z) {
  int node = blockIdx.x * 4 + (threadIdx.x >> 6);
  int lane = threadIdx.x & 63;
  float dn = dis[node];
  float acc = x[(size_t)node * 64 + lane] * dn * dn;
  int beg = offsets[node], end = offsets[node + 1];
  for (int k = beg; k < end; k++) {
    int s = csr[k];
    acc = fmaf(dn * dis[s], x[(size_t)s * 64 + lane], acc);
  }
  z[(size_t)node * 64 + lane] = acc;
}

__global__ __launch_bounds__(256) void agg128_kernel(const float* __restrict__ h,
                                                     const float* __restrict__ dis,
                                                     const int* __restrict__ offsets,
                                                     const int* __restrict__ csr,
                                                     float* __restrict__ z) {
  int node = blockIdx.x * 4 + (threadIdx.x >> 6);
  int lane = threadIdx.x & 63;
  float dn = dis[node];
  float sn = dn * dn;
  const float* hr = h + (size_t)node * 128;
  float a0 = hr[lane] * sn;
  float a1 = hr[lane + 64] * sn;
  int beg = offsets[node], end = offsets[node + 1];
  for (int k = beg; k < end; k++) {
    int s = csr[k];
    float w = dn * dis[s];
    const float* hs = h + (size_t)s * 128;
    a0 = fmaf(w, hs[lane], a0);
    a1 = fmaf(w, hs[lane + 64], a1);
  }
  z[(size_t)node * 128 + lane] = a0;
  z[(size_t)node * 128 + lane + 64] = a1;
}

// ---------------- fused fp32 GEMM: C = A[N,K] * B (+bias, +BN, +ReLU) ----------------
template <int K, int O, bool BTRANS, bool DOBN, bool DORELU>
__global__ __launch_bounds__(256) void gemm_fused(const float* __restrict__ A,
                                                  const float* __restrict__ B,
                                                  const float* __restrict__ bias,
                                                  const float* __restrict__ gamma,
                                                  const float* __restrict__ beta,
                                                  const float* __restrict__ mean,
                                                  const float* __restrict__ var,
                                                  float* __restrict__ C) {
  constexpr int BM = 64, BO = 128, BK = 16;
  __shared__ float As[BK][BM + 4];
  __shared__ float Bs[BK][BO + 4];
  int tid = threadIdx.x;
  int m0 = blockIdx.x * BM;
  int o0 = blockIdx.y * BO;
  int tm = tid >> 4;
  int to = tid & 15;

  float acc[4][8];
#pragma unroll
  for (int i = 0; i < 4; i++)
#pragma unroll
    for (int j = 0; j < 8; j++) acc[i][j] = 0.0f;

  int arow = tid >> 2, aseg = tid & 3;

  for (int k0 = 0; k0 < K; k0 += BK) {
    float4 a4 = *(const float4*)&A[(size_t)(m0 + arow) * K + k0 + aseg * 4];
    float4 b0, b1;
    int bo = 0, bkh = 0;
    if (BTRANS) {
      bo = tid & 127;
      bkh = (tid >> 7) * 8;
      const float* bp = &B[(size_t)(o0 + bo) * K + k0 + bkh];
      b0 = *(const float4*)bp;
      b1 = *(const float4*)(bp + 4);
    } else {
      bkh = tid >> 4;
      bo = (tid & 15) * 8;
      const float* bp = &B[(size_t)(k0 + bkh) * O + o0 + bo];
      b0 = *(const float4*)bp;
      b1 = *(const float4*)(bp + 4);
    }
    __syncthreads();
    As[aseg * 4 + 0][arow] = a4.x;
    As[aseg * 4 + 1][arow] = a4.y;
    As[aseg * 4 + 2][arow] = a4.z;
    As[aseg * 4 + 3][arow] = a4.w;
    if (BTRANS) {
      Bs[bkh + 0][bo] = b0.x; Bs[bkh + 1][bo] = b0.y;
      Bs[bkh + 2][bo] = b0.z; Bs[bkh + 3][bo] = b0.w;
      Bs[bkh + 4][bo] = b1.x; Bs[bkh + 5][bo] = b1.y;
      Bs[bkh + 6][bo] = b1.z; Bs[bkh + 7][bo] = b1.w;
    } else {
      *(float4*)&Bs[bkh][bo] = b0;
      *(float4*)&Bs[bkh][bo + 4] = b1;
    }
    __syncthreads();
#pragma unroll
    for (int k = 0; k < BK; k++) {
      float4 av = *(const float4*)&As[k][tm * 4];
      float4 bv0 = *(const float4*)&Bs[k][to * 8];
      float4 bv1 = *(const float4*)&Bs[k][to * 8 + 4];
      float am[4] = {av.x, av.y, av.z, av.w};
      float bm[8] = {bv0.x, bv0.y, bv0.z, bv0.w, bv1.x, bv1.y, bv1.z, bv1.w};
#pragma unroll
      for (int i = 0; i < 4; i++)
#pragma unroll
        for (int j = 0; j < 8; j++) acc[i][j] = fmaf(am[i], bm[j], acc[i][j]);
    }
  }

  float cs[8], cb[8];
#pragma unroll
  for (int j = 0; j < 8; j++) {
    int c = o0 + to * 8 + j;
    float b = bias[c];
    if (DOBN) {
      float sc = gamma[c] * rsqrtf(var[c] + BN_EPS);
      cs[j] = sc;
      cb[j] = (b - mean[c]) * sc + beta[c];
    } else {
      cs[j] = 1.0f;
      cb[j] = b;
    }
  }
#pragma unroll
  for (int i = 0; i < 4; i++) {
    int row = m0 + tm * 4 + i;
    float out[8];
#pragma unroll
    for (int j = 0; j < 8; j++) {
      float v = fmaf(acc[i][j], cs[j], cb[j]);
      out[j] = DORELU ? fmaxf(v, 0.0f) : v;
    }
    float4* cp = (float4*)&C[(size_t)row * O + o0 + to * 8];
    cp[0] = make_float4(out[0], out[1], out[2], out[3]);
    cp[1] = make_float4(out[4], out[5], out[6], out[7]);
  }
}

// ---------------- key-norm max per (graph, head): bound for softmax shift ----------------
__global__ __launch_bounds__(256) void knorm_kernel(const float* __restrict__ qkv,
                                                    float* __restrict__ kmax2) {
  int g = blockIdx.x >> 2;
  int h = blockIdx.x & 3;
  size_t gbase = (size_t)g * NPG;
  float best = 0.0f;
#pragma unroll
  for (int r = 0; r < 2; r++) {
    int j = r * 256 + threadIdx.x;
    const float* kp = &qkv[(gbase + j) * 384 + 128 + h * 32];
    float s = 0.0f;
#pragma unroll
    for (int i = 0; i < 8; i++) {
      float4 v = *(const float4*)(kp + i * 4);
      s = fmaf(v.x, v.x, s);
      s = fmaf(v.y, v.y, s);
      s = fmaf(v.z, v.z, s);
      s = fmaf(v.w, v.w, s);
    }
    best = fmaxf(best, s);
  }
#pragma unroll
  for (int off = 32; off >= 1; off >>= 1)
    best = fmaxf(best, __shfl_xor(best, off, 64));
  __shared__ float red[4];
  int wave = threadIdx.x >> 6;
  if ((threadIdx.x & 63) == 0) red[wave] = best;
  __syncthreads();
  if (threadIdx.x == 0) {
    float m = fmaxf(fmaxf(red[0], red[1]), fmaxf(red[2], red[3]));
    kmax2[blockIdx.x] = m;
  }
}

// ---------------- attention: 1 query/thread, single pass, bound-shifted softmax ----------
// grid: 128 graphs x 4 heads x 2 query-chunks = 1024 blocks, 256 threads
__global__ __launch_bounds__(256, 4) void attn_kernel(const float* __restrict__ qkv,
                                                      const float* __restrict__ kmax2,
                                                      float* __restrict__ obuf) {
  int b = blockIdx.x;
  int g = b >> 3;
  int h = (b >> 1) & 3;
  int cq = b & 1;
  int t = threadIdx.x;
  const float scale = 0.17677669529663687f;  // 1/sqrt(32)
  size_t gbase = (size_t)g * NPG;
  int qi = cq * 256 + t;

  __shared__ float sk[128][36];  // pad 36: staging writes <=8-way; reads are broadcast
  __shared__ float sv[128][36];

  // q, pre-scaled by 1/sqrt(dh)
  float q[32];
  float qn2 = 0.0f;
  {
    const float* qp = &qkv[(gbase + qi) * 384 + h * 32];
#pragma unroll
    for (int i = 0; i < 8; i++) {
      float4 v = *(const float4*)(qp + i * 4);
      q[i * 4 + 0] = v.x * scale;
      q[i * 4 + 1] = v.y * scale;
      q[i * 4 + 2] = v.z * scale;
      q[i * 4 + 3] = v.w * scale;
    }
#pragma unroll
    for (int d = 0; d < 32; d++) qn2 = fmaf(q[d], q[d], qn2);
  }
  // M >= max_j (q . k_j) by Cauchy-Schwarz; softmax is shift-invariant for any M >= max
  float M = sqrtf(qn2 * kmax2[g * 4 + h]);

  float o[32];
#pragma unroll
  for (int d = 0; d < 32; d++) o[d] = 0.0f;
  float l = 0.0f;

  int sr = t & 127;           // staged row
  int kv = t >> 7;            // 0 -> k, 1 -> v
  for (int c = 0; c < 4; c++) {
    __syncthreads();
    {
      const float* gp = &qkv[(gbase + c * 128 + sr) * 384 + 128 + kv * 128 + h * 32];
      float* sp = kv ? &sv[sr][0] : &sk[sr][0];
#pragma unroll
      for (int i = 0; i < 8; i += 2) {
        float4 v0 = *(const float4*)(gp + i * 4);
        float4 v1 = *(const float4*)(gp + i * 4 + 4);
        *(float4*)(sp + i * 4) = v0;
        *(float4*)(sp + i * 4 + 4) = v1;
      }
    }
    __syncthreads();
#pragma unroll 2
    for (int j = 0; j < 128; j++) {
      float s = 0.0f;
#pragma unroll
      for (int i = 0; i < 8; i++) {
        float4 kvv = *(const float4*)&sk[j][i * 4];
        s = fmaf(q[i * 4 + 0], kvv.x, s);
        s = fmaf(q[i * 4 + 1], kvv.y, s);
        s = fmaf(q[i * 4 + 2], kvv.z, s);
        s = fmaf(q[i * 4 + 3], kvv.w, s);
      }
      float p = __expf(s - M);
      l += p;
#pragma unroll
      for (int i = 0; i < 8; i++) {
        float4 vv = *(const float4*)&sv[j][i * 4];
        o[i * 4 + 0] = fmaf(p, vv.x, o[i * 4 + 0]);
        o[i * 4 + 1] = fmaf(p, vv.y, o[i * 4 + 1]);
        o[i * 4 + 2] = fmaf(p, vv.z, o[i * 4 + 2]);
        o[i * 4 + 3] = fmaf(p, vv.w, o[i * 4 + 3]);
      }
    }
  }

  float inv = 1.0f / l;
  float* op = &obuf[(gbase + qi) * 128 + h * 32];
#pragma unroll
  for (int i = 0; i < 8; i++) {
    *(float4*)(op + i * 4) = make_float4(o[i * 4 + 0] * inv, o[i * 4 + 1] * inv,
                                         o[i * 4 + 2] * inv, o[i * 4 + 3] * inv);
  }
}

// ---------------- mean pool ----------------
__global__ __launch_bounds__(128) void pool_kernel(const float* __restrict__ fin,
                                                   float* __restrict__ emb) {
  int g = blockIdx.x, c = threadIdx.x;
  const float* p = fin + (size_t)g * NPG * HID + c;
  float s = 0.0f;
  for (int i = 0; i < NPG; i++) s += p[(size_t)i * HID];
  emb[g * HID + c] = s * (1.0f / NPG);
}

extern "C" void kernel_launch(void* const* d_in, const int* in_sizes, int n_in,
                              void* d_out, int out_size, void* d_ws, size_t ws_size,
                              hipStream_t stream) {
  (void)in_sizes; (void)n_in; (void)out_size; (void)ws_size;
  const float* x          = (const float*)d_in[0];
  const float* W0         = (const float*)d_in[1];
  const float* b0         = (const float*)d_in[2];
  const float* Wh         = (const float*)d_in[3];
  const float* bh         = (const float*)d_in[4];
  const float* bn_gamma   = (const float*)d_in[5];
  const float* bn_beta    = (const float*)d_in[6];
  const float* bn_mean    = (const float*)d_in[7];
  const float* bn_var     = (const float*)d_in[8];
  const float* attn_in_w  = (const float*)d_in[9];
  const float* attn_in_b  = (const float*)d_in[10];
  const float* attn_out_w = (const float*)d_in[11];
  const float* attn_out_b = (const float*)d_in[12];
  const int* edge_index   = (const int*)d_in[13];
  const int* src = edge_index;
  const int* dst = edge_index + N_EDGES;

  char* ws = (char*)d_ws;
  size_t off = 0;
  auto alloc = [&](size_t bytes) -> void* {
    void* p = ws + off;
    off += (bytes + 255) & ~(size_t)255;
    return p;
  };
  int*   deg     = (int*)alloc((size_t)N_NODES * 4);
  int*   offsets = (int*)alloc((size_t)(N_NODES + 1) * 4);
  int*   cursor  = (int*)alloc((size_t)N_NODES * 4);
  int*   csr     = (int*)alloc((size_t)N_EDGES * 4);
  float* dis     = (float*)alloc((size_t)N_NODES * 4);
  float* bufA    = (float*)alloc((size_t)N_NODES * HID * 4);
  float* bufB    = (float*)alloc((size_t)N_NODES * HID * 4);
  float* qkvb    = (float*)alloc((size_t)N_NODES * 384 * 4);
  float* kmax2   = (float*)alloc((size_t)N_GRAPHS * 4 * 4);

  float* fin = (float*)d_out;                       // [N, HID]
  float* emb = fin + (size_t)N_NODES * HID;         // [G, HID]

  hipMemsetAsync(deg, 0, (size_t)N_NODES * 4, stream);
  hist_kernel<<<N_EDGES / 256, 256, 0, stream>>>(dst, deg);
  dis_kernel<<<N_NODES / 256, 256, 0, stream>>>(deg, dis);
  scan_kernel<<<1, 1024, 0, stream>>>(deg, offsets, cursor);
  fill_kernel<<<N_EDGES / 256, 256, 0, stream>>>(src, dst, cursor, csr);

  dim3 gemm_grid(N_NODES / 64, 1);
  agg64_kernel<<<N_NODES / 4, 256, 0, stream>>>(x, dis, offsets, csr, bufB);
  gemm_fused<64, 128, false, true, true><<<gemm_grid, 256, 0, stream>>>(
      bufB, W0, b0, bn_gamma, bn_beta, bn_mean, bn_var, bufA);
  for (int L = 0; L < 3; L++) {
    agg128_kernel<<<N_NODES / 4, 256, 0, stream>>>(bufA, dis, offsets, csr, bufB);
    gemm_fused<128, 128, false, true, true><<<gemm_grid, 256, 0, stream>>>(
        bufB, Wh + (size_t)L * HID * HID, bh + (size_t)L * HID,
        bn_gamma + (size_t)(L + 1) * HID, bn_beta + (size_t)(L + 1) * HID,
        bn_mean + (size_t)(L + 1) * HID, bn_var + (size_t)(L + 1) * HID, bufA);
  }
  dim3 qkv_grid(N_NODES / 64, 3);
  gemm_fused<128, 384, true, false, false><<<qkv_grid, 256, 0, stream>>>(
      bufA, attn_in_w, attn_in_b, nullptr, nullptr, nullptr, nullptr, qkvb);
  knorm_kernel<<<N_GRAPHS * 4, 256, 0, stream>>>(qkvb, kmax2);
  attn_kernel<<<N_GRAPHS * 4 * 2, 256, 0, stream>>>(qkvb, kmax2, bufB);
  gemm_fused<128, 128, true, false, false><<<gemm_grid, 256, 0, stream>>>(
      bufB, attn_out_w, attn_out_b, nullptr, nullptr, nullptr, nullptr, fin);
  pool_kernel<<<N_GRAPHS, 128, 0, stream>>>(fin, emb);
}